// Round 3
// baseline (532.549 us; speedup 1.0000x reference)
//
#include <hip/hip_runtime.h>
#include <hip/hip_bf16.h>

// GATv2 x3 layers, MI355X. f32 in/out; edge_index int32.
// R15: lane-per-channel k_score. One wave = 32 edges x one head; lane c owns
// channel c. xl row reads fully coalesced (256B/row), W+att hoisted to regs,
// ea via wave-uniform scalar loads from a pair-interleaved ea2 buffer
// (built once, covers real edges + self loops + pad -> branch-free loop).
// 2 edges packed per f2 lane (v_pk_fma, 64b SGPR ea operand). Per-wave LDS
// transpose for the 64-lane score reduce. Keeps head-major xl + head-
// clustered XCD mapping (L2-resident gathers).

#define NN 10000    // nodes
#define NE 200000   // edges
#define ND 128      // node dim (layer 0 input)
#define ED 16       // edge dim
#define CD 64       // conv dim (per head)
#define NH 5        // heads
#define HC 320      // NH*CD
#define EF 210000   // NE + NN (with self loops)
#define EFP 210048  // EF padded to 64
#define NEG 0.2f
#define WPH 1641    // k_score blocks per head = EFP/128
#define TOT2 8205   // WPH*NH
#define G2 8208     // launched blocks (8 XCDs * 1026), guard wk>=TOT2

typedef float f2 __attribute__((ext_vector_type(2)));

// ---- CSR build: count ----
__global__ void k_count(const int* __restrict__ dst, int* __restrict__ deg) {
  int e = blockIdx.x * blockDim.x + threadIdx.x;
  if (e >= NE) return;
  atomicAdd(&deg[dst[e]], 1);
}

// ---- CSR build: exclusive scan (single block, 1024 threads x 10 elems) ----
__global__ __launch_bounds__(1024) void k_scan(const int* __restrict__ deg,
                                               int* __restrict__ rowptr) {
  __shared__ int part[1024];
  int t = threadIdx.x;
  int base = t * 10;
  int local[10];
  int s = 0;
  #pragma unroll
  for (int j = 0; j < 10; j++) {
    int i = base + j;
    local[j] = (i < NN) ? deg[i] : 0;
    s += local[j];
  }
  part[t] = s;
  __syncthreads();
  for (int off = 1; off < 1024; off <<= 1) {
    int v = (t >= off) ? part[t - off] : 0;
    __syncthreads();
    part[t] += v;
    __syncthreads();
  }
  int prefix = (t > 0) ? part[t - 1] : 0;
  #pragma unroll
  for (int j = 0; j < 10; j++) {
    int i = base + j;
    if (i < NN) rowptr[i] = prefix;
    prefix += local[j];
  }
  if (t == 1023) rowptr[NN] = prefix;
}

// ---- CSR build: fill (writes into extended src/dst arrays) ----
__global__ void k_fill(const int* __restrict__ ei, const int* __restrict__ rowptr,
                       int* __restrict__ cursor, int* __restrict__ csr_eid,
                       int* __restrict__ srcx, int* __restrict__ dstx) {
  int e = blockIdx.x * blockDim.x + threadIdx.x;
  if (e >= NE) return;
  int d = ei[NE + e];
  int slot = atomicAdd(&cursor[d], 1);
  int pos = rowptr[d] + slot;
  csr_eid[pos] = e;
  srcx[pos] = ei[e];
  dstx[pos] = d;
}

// ---- extend src/dst with self loops + pad ----
__global__ void k_selfext(int* __restrict__ srcx, int* __restrict__ dstx) {
  int i = blockIdx.x * blockDim.x + threadIdx.x;
  int p = NE + i;
  if (p >= EFP) return;
  int v = (p < EF) ? (p - NE) : 0;
  srcx[p] = v;
  dstx[p] = v;
}

// ---- loop_attr = mean of incoming edge_attr (gather, wave per node) ----
__global__ __launch_bounds__(256) void k_loopattr(const int* __restrict__ csr_eid,
                                                  const int* __restrict__ rowptr,
                                                  const float* __restrict__ eattr,
                                                  float* __restrict__ loop_attr) {
  int wave = threadIdx.x >> 6, lane = threadIdx.x & 63;
  int d = blockIdx.x * 4 + wave;
  if (d >= NN) return;
  int g = lane >> 4, k = lane & 15;
  int b = rowptr[d], n = rowptr[d + 1] - b;
  float s = 0.f;
  for (int i = g; i < n; i += 4)
    s += eattr[(size_t)csr_eid[b + i] * ED + k];
  s += __shfl_xor(s, 16, 64);
  s += __shfl_xor(s, 32, 64);
  if (g == 0) loop_attr[d * ED + k] = s / fmaxf((float)n, 1.0f);
}

// ---- ea2: pair-interleaved edge attrs over ALL EFP positions ----
// ea2[(p>>1)*32 + 2*k + (p&1)] = attr(p)[k]; attr = eattr[eid] | loop_attr | 0
__global__ void k_ea2(const int* __restrict__ csr_eid, const float* __restrict__ eattr,
                      const float* __restrict__ loop_attr, float* __restrict__ ea2) {
  int idx = blockIdx.x * blockDim.x + threadIdx.x;  // p*16 + k
  if (idx >= EFP * ED) return;
  int p = idx >> 4, k = idx & 15;
  float v;
  if (p < NE)      v = eattr[(size_t)csr_eid[p] * ED + k];
  else if (p < EF) v = loop_attr[(size_t)(p - NE) * ED + k];
  else             v = 0.f;
  ea2[((size_t)(p >> 1) * 32) + 2 * k + (p & 1)] = v;
}

// ---- xl = h @ Wl + bl  (no LDS; h rows via uniform broadcast loads) ----
// Output layout: head-major xl[h][node][c], h slice = NN*CD floats (2.56MB).
template <int D>
__global__ __launch_bounds__(320) void k_xl(const float* __restrict__ h,
                                            const float* __restrict__ Wl,
                                            const float* __restrict__ bl,
                                            float* __restrict__ xl) {
  constexpr int NPB = 8;
  int node0 = blockIdx.x * NPB;
  int t = threadIdx.x;  // output column 0..319
  float acc[NPB];
  #pragma unroll
  for (int i = 0; i < NPB; i++) acc[i] = 0.f;
  for (int k = 0; k < D; k += 4) {
    float w0 = Wl[(k + 0) * HC + t];
    float w1 = Wl[(k + 1) * HC + t];
    float w2 = Wl[(k + 2) * HC + t];
    float w3 = Wl[(k + 3) * HC + t];
    #pragma unroll
    for (int i = 0; i < NPB; i++) {
      float4 hv = *(const float4*)(h + (size_t)(node0 + i) * D + k);
      acc[i] += hv.x * w0 + hv.y * w1 + hv.z * w2 + hv.w * w3;
    }
  }
  float bv = bl[t];
  int hh = t >> 6, c = t & 63;  // head, channel (CD=64)
  #pragma unroll
  for (int i = 0; i < NPB; i++)
    xl[((size_t)hh * NN + node0 + i) * CD + c] = acc[i] + bv;
}

// ---- scores: WAVE PER 32 EDGES x HEAD, LANE PER CHANNEL ----
// Per iteration: 2 edges packed in f2. xl reads coalesced (row = 256B).
// W[k][c], att[c] hoisted in regs. ea via uniform (scalar) loads from ea2.
// LDS transpose per wave for the 64-lane score reduction (no barrier).
__global__ __launch_bounds__(256) void k_score(
    const int* __restrict__ srcx, const int* __restrict__ dstx,
    const float* __restrict__ ea2, const float* __restrict__ xl,
    const float* __restrict__ We, const float* __restrict__ att,
    float* __restrict__ wP) {
  __shared__ float lds[4][64][34];
  int wk = (blockIdx.x & 7) * 1026 + (blockIdx.x >> 3);  // contiguous per XCD
  if (wk >= TOT2) return;
  int h  = wk / WPH;                                     // uniform
  int lb = wk - h * WPH;
  int wave = __builtin_amdgcn_readfirstlane(threadIdx.x >> 6);
  int lane = threadIdx.x & 63;
  int p0 = lb * 128 + wave * 32;                         // uniform

  // hoist W (16 regs as f2 splats) and att
  f2 wv[16];
  #pragma unroll
  for (int k = 0; k < 16; k++) {
    float w = We[k * HC + h * CD + lane];
    wv[k] = f2{w, w};
  }
  float a1 = att[h * CD + lane];
  f2 av = f2{a1, a1};
  const float* xh = xl + (size_t)h * NN * CD;  // head slice (L2-resident)
  const f2 zero = {0.f, 0.f};

  f2 acc[16];
  #pragma unroll
  for (int i = 0; i < 16; i++) {
    int p = p0 + 2 * i;
    int s0 = srcx[p], s1 = srcx[p + 1];        // uniform -> s_load
    int d0 = dstx[p], d1 = dstx[p + 1];
    const f2* e = (const f2*)(ea2 + (size_t)(p >> 1) * 32);  // uniform
    float xs0 = xh[(size_t)s0 * CD + lane];    // coalesced 256B row
    float xs1 = xh[(size_t)s1 * CD + lane];
    float xd0 = xh[(size_t)d0 * CD + lane];
    float xd1 = xh[(size_t)d1 * CD + lane];
    f2 z = f2{xs0 + xd0, xs1 + xd1};
    #pragma unroll
    for (int k = 0; k < 16; k++)
      z += e[k] * wv[k];                       // v_pk_fma, sgpr-pair operand
    z = __builtin_elementwise_max(z, zero) + NEG * __builtin_elementwise_min(z, zero);
    acc[i] = z * av;
  }

  // transpose-reduce: lane c holds 32 edge-partials -> lane j holds score[j]
  float (*L)[34] = lds[wave];
  #pragma unroll
  for (int i = 0; i < 16; i++)
    *(f2*)&L[lane][2 * i] = acc[i];            // bank-pair 2-way (free)
  int part = lane >> 5, j = lane & 31;
  float sum = 0.f;
  #pragma unroll
  for (int r = 0; r < 32; r++)
    sum += L[part * 32 + r][j];                // conflict-free
  sum += __shfl_xor(sum, 32, 64);
  if (part == 0) {
    float sc = fminf(fmaxf(sum, -60.f), 60.f);
    wP[(size_t)h * EFP + p0 + j] = __expf(sc); // coalesced 128B store
  }
}

// ---- aggregation: block per node, wave per head; single pass (no max/exp) --
__global__ __launch_bounds__(320) void k_agg(
    const int* __restrict__ csr_src, const int* __restrict__ rowptr,
    const float* __restrict__ wP, const float* __restrict__ xl,
    const float* __restrict__ bias, float* __restrict__ out) {
  __shared__ float s_v[NH][CD];
  int h = threadIdx.x >> 6, lane = threadIdx.x & 63;
  int d = blockIdx.x;
  int b = rowptr[d], n = rowptr[d + 1] - b;
  const float* sp = wP + (size_t)h * EFP;
  const float* xlh = xl + (size_t)h * NN * CD + lane;  // head-major layout
  // self loop init
  float dn = sp[NE + d];
  float acc = dn * xlh[(size_t)d * CD];
  // edge loop, unroll 4 (uniform w addrs -> scalar loads)
  int p = b, pe = b + n;
  for (; p + 4 <= pe; p += 4) {
    int s0 = csr_src[p], s1 = csr_src[p + 1], s2 = csr_src[p + 2], s3 = csr_src[p + 3];
    float w0 = sp[p], w1 = sp[p + 1], w2 = sp[p + 2], w3 = sp[p + 3];
    float x0 = xlh[(size_t)s0 * CD];
    float x1 = xlh[(size_t)s1 * CD];
    float x2 = xlh[(size_t)s2 * CD];
    float x3 = xlh[(size_t)s3 * CD];
    dn += (w0 + w1) + (w2 + w3);
    acc += w0 * x0 + w1 * x1 + w2 * x2 + w3 * x3;
  }
  for (; p < pe; p++) {
    int s0 = csr_src[p];
    float w0 = sp[p];
    dn += w0;
    acc += w0 * xlh[(size_t)s0 * CD];
  }
  s_v[h][lane] = acc / dn;
  __syncthreads();
  if (h == 0) {
    float v = s_v[0][lane] + s_v[1][lane] + s_v[2][lane] + s_v[3][lane] + s_v[4][lane];
    v = v * (1.0f / NH) + bias[lane];
    v = v > 0.f ? v : expm1f(v);
    out[(size_t)d * CD + lane] = v;
  }
}

static inline size_t aln(size_t x) { return (x + 255) & ~(size_t)255; }

extern "C" void kernel_launch(void* const* d_in, const int* in_sizes, int n_in,
                              void* d_out, int out_size, void* d_ws, size_t ws_size,
                              hipStream_t stream) {
  const float* x = (const float*)d_in[0];
  const int* ei = (const int*)d_in[1];      // [2, NE]: src row then dst row
  const float* eattr = (const float*)d_in[2];

  char* w = (char*)d_ws;
  int* degi      = (int*)w;                 w += aln(NN * 4);
  int* cursor    = (int*)w;                 w += aln(NN * 4);
  int* rowptr    = (int*)w;                 w += aln((NN + 1) * 4);
  int* csr_eid   = (int*)w;                 w += aln((size_t)NE * 4);
  int* srcx      = (int*)w;                 w += aln((size_t)EFP * 4);
  int* dstx      = (int*)w;                 w += aln((size_t)EFP * 4);
  float* loop_attr = (float*)w;             w += aln((size_t)NN * ED * 4);
  float* ea2     = (float*)w;               w += aln((size_t)EFP * ED * 4);
  float* xl      = (float*)w;               w += aln((size_t)NN * HC * 4);
  float* wPbuf   = (float*)w;               w += aln((size_t)NH * EFP * 4);
  float* hbuf    = (float*)w;               w += aln((size_t)NN * CD * 4);

  // graph structure + permuted edge attrs (layer-invariant)
  hipMemsetAsync(degi, 0, NN * 4, stream);
  hipMemsetAsync(cursor, 0, NN * 4, stream);
  k_count<<<(NE + 255) / 256, 256, 0, stream>>>(ei + NE, degi);
  k_scan<<<1, 1024, 0, stream>>>(degi, rowptr);
  k_fill<<<(NE + 255) / 256, 256, 0, stream>>>(ei, rowptr, cursor, csr_eid, srcx, dstx);
  k_selfext<<<(EFP - NE + 255) / 256, 256, 0, stream>>>(srcx, dstx);
  k_loopattr<<<(NN + 3) / 4, 256, 0, stream>>>(csr_eid, rowptr, eattr, loop_attr);
  k_ea2<<<(EFP * ED + 255) / 256, 256, 0, stream>>>(csr_eid, eattr, loop_attr, ea2);

  for (int l = 0; l < 3; l++) {
    const float* Wl  = (const float*)d_in[3 + 5 * l];
    const float* bl  = (const float*)d_in[4 + 5 * l];
    const float* We  = (const float*)d_in[5 + 5 * l];
    const float* att = (const float*)d_in[6 + 5 * l];
    const float* b   = (const float*)d_in[7 + 5 * l];

    if (l == 0) k_xl<ND><<<NN / 8, 320, 0, stream>>>(x, Wl, bl, xl);
    else        k_xl<CD><<<NN / 8, 320, 0, stream>>>(hbuf, Wl, bl, xl);

    k_score<<<G2, 256, 0, stream>>>(srcx, dstx, ea2, xl, We, att, wPbuf);

    float* dst_out = (l < 2) ? hbuf : (float*)d_out;
    k_agg<<<NN, 320, 0, stream>>>(srcx, rowptr, wPbuf, xl, b, dst_out);
  }
}